// Round 1
// baseline (8017.780 us; speedup 1.0000x reference)
//
#include <hip/hip_runtime.h>
#include <hip/hip_bf16.h>

#define NNODE 50000
#define NEDGE 300000
#define DDIM 256
#define NHEAD 8
#define DHEAD 32

static const float DECAY0 = 1.0f;
static const float DECAY1 = 0.60653065971263342f;
static const float DECAY2 = 0.36787944117144233f;

// ---------------- GEMM: C[M,256] = epilogue( (A[M,256]+in_bias) @ W[256,256] + out_bias )
// epilogue: optional leaky_relu(slope); optional accumulate C += decay*val
__global__ __launch_bounds__(256) void gemm256(
    const float* __restrict__ A, const float* __restrict__ W, float* __restrict__ C,
    int M, const float* __restrict__ in_bias, const float* __restrict__ out_bias,
    float slope, int do_act, int accum, float decay)
{
    __shared__ float As[16][65];   // [k][m], padded
    __shared__ float Ws[16][64];   // [k][n]
    const int tid  = threadIdx.x;
    const int bm   = blockIdx.x * 64;
    const int bn   = blockIdx.y * 64;
    const int trow = tid >> 4;          // 0..15
    const int tcol = tid & 15;          // 0..15
    const int arow = tid >> 2;          // 0..63
    const int acol = (tid & 3) << 2;    // 0,4,8,12
    const int wrow = tid >> 4;          // 0..15
    const int wcol = (tid & 15) << 2;   // 0..60

    float acc[4][4];
#pragma unroll
    for (int i = 0; i < 4; i++)
#pragma unroll
        for (int j = 0; j < 4; j++) acc[i][j] = 0.f;

    const int  gm   = bm + arow;
    const bool aval = (gm < M);

    for (int k0 = 0; k0 < 256; k0 += 16) {
        float4 av = make_float4(0.f, 0.f, 0.f, 0.f);
        if (aval) {
            av = *reinterpret_cast<const float4*>(A + (size_t)gm * 256 + k0 + acol);
            if (in_bias) {
                av.x += in_bias[k0 + acol + 0];
                av.y += in_bias[k0 + acol + 1];
                av.z += in_bias[k0 + acol + 2];
                av.w += in_bias[k0 + acol + 3];
            }
        }
        float4 wv = *reinterpret_cast<const float4*>(W + (size_t)(k0 + wrow) * 256 + bn + wcol);
        __syncthreads();
        As[acol + 0][arow] = av.x;
        As[acol + 1][arow] = av.y;
        As[acol + 2][arow] = av.z;
        As[acol + 3][arow] = av.w;
        *reinterpret_cast<float4*>(&Ws[wrow][wcol]) = wv;
        __syncthreads();
#pragma unroll
        for (int kk = 0; kk < 16; kk++) {
            const float a0 = As[kk][trow * 4 + 0];
            const float a1 = As[kk][trow * 4 + 1];
            const float a2 = As[kk][trow * 4 + 2];
            const float a3 = As[kk][trow * 4 + 3];
            const float4 b = *reinterpret_cast<const float4*>(&Ws[kk][tcol * 4]);
            acc[0][0] += a0 * b.x; acc[0][1] += a0 * b.y; acc[0][2] += a0 * b.z; acc[0][3] += a0 * b.w;
            acc[1][0] += a1 * b.x; acc[1][1] += a1 * b.y; acc[1][2] += a1 * b.z; acc[1][3] += a1 * b.w;
            acc[2][0] += a2 * b.x; acc[2][1] += a2 * b.y; acc[2][2] += a2 * b.z; acc[2][3] += a2 * b.w;
            acc[3][0] += a3 * b.x; acc[3][1] += a3 * b.y; acc[3][2] += a3 * b.z; acc[3][3] += a3 * b.w;
        }
    }

#pragma unroll
    for (int i = 0; i < 4; i++) {
        const int row = bm + trow * 4 + i;
        if (row >= M) continue;
        float vals[4];
#pragma unroll
        for (int j = 0; j < 4; j++) {
            float v = acc[i][j];
            if (out_bias) v += out_bias[bn + tcol * 4 + j];
            if (do_act) v = (v > 0.f) ? v : slope * v;
            vals[j] = v;
        }
        float* cp = C + (size_t)row * 256 + bn + tcol * 4;
        if (accum) {
            float4 prev = *reinterpret_cast<float4*>(cp);
            prev.x += decay * vals[0];
            prev.y += decay * vals[1];
            prev.z += decay * vals[2];
            prev.w += decay * vals[3];
            *reinterpret_cast<float4*>(cp) = prev;
        } else {
            *reinterpret_cast<float4*>(cp) = make_float4(vals[0], vals[1], vals[2], vals[3]);
        }
    }
}

// ---------------- alpha_s/alpha_d: [N,8] head-wise dot of hproj row with att vectors
__global__ __launch_bounds__(256) void alpha_kernel(
    const float* __restrict__ hproj, const float* __restrict__ att_s,
    const float* __restrict__ att_d, float* __restrict__ alpha_s, float* __restrict__ alpha_d)
{
    const int n = blockIdx.x;
    const int t = threadIdx.x;
    const float v  = hproj[(size_t)n * 256 + t];
    float ps = v * att_s[t];
    float pd = v * att_d[t];
#pragma unroll
    for (int off = 16; off > 0; off >>= 1) {
        ps += __shfl_xor(ps, off, 32);
        pd += __shfl_xor(pd, off, 32);
    }
    if ((t & 31) == 0) {
        alpha_s[n * 8 + (t >> 5)] = ps;
        alpha_d[n * 8 + (t >> 5)] = pd;
    }
}

__device__ __forceinline__ unsigned fkey(float f) {
    unsigned b = __float_as_uint(f);
    return (b & 0x80000000u) ? ~b : (b | 0x80000000u);
}
__device__ __forceinline__ float fdec(unsigned k) {
    return __uint_as_float((k & 0x80000000u) ? (k ^ 0x80000000u) : ~k);
}

// ---------------- edge pass A: e = lrelu(as[src]+ad[dst], 0.2); atomicMax m[dst]
__global__ __launch_bounds__(256) void edge_a(
    const int* __restrict__ src, const int* __restrict__ dst,
    const float* __restrict__ alpha_s, const float* __restrict__ alpha_d,
    float* __restrict__ e_buf, unsigned* __restrict__ mkey)
{
    const int gid = blockIdx.x * 256 + threadIdx.x;
    if (gid >= NEDGE * 8) return;
    const int e = gid >> 3, h = gid & 7;
    const int s = src[e], d = dst[e];
    float v = alpha_s[s * 8 + h] + alpha_d[d * 8 + h];
    v = (v > 0.f) ? v : 0.2f * v;
    e_buf[gid] = v;
    atomicMax(&mkey[d * 8 + h], fkey(v));
}

// ---------------- edge pass B: p = exp(e - m[dst]); atomicAdd s[dst]
__global__ __launch_bounds__(256) void edge_b(
    const int* __restrict__ dst, float* __restrict__ e_buf,
    const unsigned* __restrict__ mkey, float* __restrict__ ssum)
{
    const int gid = blockIdx.x * 256 + threadIdx.x;
    if (gid >= NEDGE * 8) return;
    const int e = gid >> 3, h = gid & 7;
    const int d = dst[e];
    const float m = fdec(mkey[d * 8 + h]);
    const float p = __expf(e_buf[gid] - m);
    e_buf[gid] = p;
    atomicAdd(&ssum[d * 8 + h], p);
}

// ---------------- edge pass C: one wave per edge; scatter 256-float message
__global__ __launch_bounds__(256) void edge_c(
    const int* __restrict__ src, const int* __restrict__ dst,
    const float* __restrict__ e_buf, const float* __restrict__ ssum,
    const float* __restrict__ hproj, float* __restrict__ gat_out)
{
    const int wave = (blockIdx.x * 256 + threadIdx.x) >> 6;
    const int lane = threadIdx.x & 63;
    if (wave >= NEDGE) return;
    const int s = src[wave], d = dst[wave];
    const int h = lane >> 3;  // (lane*4)/32
    const float a = e_buf[wave * 8 + h] / (ssum[d * 8 + h] + 1e-16f);
    const float4 hv = *reinterpret_cast<const float4*>(hproj + (size_t)s * 256 + lane * 4);
    float* out = gat_out + (size_t)d * 256 + lane * 4;
    atomicAdd(out + 0, hv.x * a);
    atomicAdd(out + 1, hv.y * a);
    atomicAdd(out + 2, hv.z * a);
    atomicAdd(out + 3, hv.w * a);
}

// ---------------- LayerNorm + residual (in-place on h)
__global__ __launch_bounds__(256) void ln_kernel(
    const float* __restrict__ accb, float* __restrict__ h,
    const float* __restrict__ lns, const float* __restrict__ lnb)
{
    const int n = blockIdx.x;
    const int t = threadIdx.x;
    const float a = accb[(size_t)n * 256 + t];
    __shared__ float red[256];
    red[t] = a;
    __syncthreads();
    for (int off = 128; off > 0; off >>= 1) {
        if (t < off) red[t] += red[t + off];
        __syncthreads();
    }
    const float mu = red[0] * (1.f / 256.f);
    __syncthreads();
    const float dv = a - mu;
    red[t] = dv * dv;
    __syncthreads();
    for (int off = 128; off > 0; off >>= 1) {
        if (t < off) red[t] += red[t + off];
        __syncthreads();
    }
    const float var = red[0] * (1.f / 256.f);
    const float r = rsqrtf(var + 1e-5f);
    const size_t idx = (size_t)n * 256 + t;
    h[idx] = dv * r * lns[t] + lnb[t] + h[idx];
}

extern "C" void kernel_launch(void* const* d_in, const int* in_sizes, int n_in,
                              void* d_out, int out_size, void* d_ws, size_t ws_size,
                              hipStream_t stream) {
    const float* x      = (const float*)d_in[0];
    const int*   edges  = (const int*)  d_in[1];
    const float* lin1_w = (const float*)d_in[2];
    const float* lin1_b = (const float*)d_in[3];
    const float* gat_w  = (const float*)d_in[4];
    const float* att_s  = (const float*)d_in[5];
    const float* att_d  = (const float*)d_in[6];
    const float* gat_b  = (const float*)d_in[7];
    const float* dec_w  = (const float*)d_in[8];
    const float* dec_b  = (const float*)d_in[9];
    const float* ln_s   = (const float*)d_in[10];
    const float* ln_b   = (const float*)d_in[11];

    float* h = (float*)d_out;              // current node features live in d_out
    const size_t NF = (size_t)NNODE * 256;
    const size_t N8 = (size_t)NNODE * 8;

    float*    acc_buf = (float*)d_ws;
    float*    hproj   = acc_buf + NF;
    float*    gat_out = hproj + NF;
    unsigned* mkey    = (unsigned*)(gat_out + NF);
    float*    ssum    = (float*)(mkey + N8);
    float*    as_     = ssum + N8;
    float*    ad_     = as_ + N8;
    float*    e_buf   = ad_ + N8;

    const float decays[3] = {DECAY0, DECAY1, DECAY2};

    dim3 gg((NNODE + 63) / 64, 4);
    const int eb = (NEDGE * 8 + 255) / 256;
    const int cb = (NEDGE * 64) / 256;

    // h = leaky_relu(x @ lin1_w + lin1_b, 0.01)
    gemm256<<<gg, 256, 0, stream>>>(x, lin1_w, h, NNODE, nullptr, lin1_b, 0.01f, 1, 0, 0.f);

    for (int l = 0; l < 2; l++) {
        hipMemsetAsync(acc_buf, 0, NF * 4, stream);
        for (int k = 0; k < 3; k++) {
            const int lk = l * 3 + k;
            // zero gat_out, mkey, ssum (contiguous)
            hipMemsetAsync(gat_out, 0, (NF + 2 * N8) * 4, stream);
            // hproj = h @ gat_w[l,k]
            gemm256<<<gg, 256, 0, stream>>>(h, gat_w + (size_t)lk * 65536, hproj, NNODE,
                                            nullptr, nullptr, 0.f, 0, 0, 0.f);
            // per-node attention logits
            alpha_kernel<<<NNODE, 256, 0, stream>>>(hproj, att_s + lk * 256, att_d + lk * 256,
                                                    as_, ad_);
            const int* srcp = edges + (size_t)k * 2 * NEDGE;
            const int* dstp = srcp + NEDGE;
            edge_a<<<eb, 256, 0, stream>>>(srcp, dstp, as_, ad_, e_buf, mkey);
            edge_b<<<eb, 256, 0, stream>>>(dstp, e_buf, mkey, ssum);
            edge_c<<<cb, 256, 0, stream>>>(srcp, dstp, e_buf, ssum, hproj, gat_out);
            // acc += decay[k] * lrelu((gat_out + gat_bias) @ dec_w + dec_b, 0.01)
            gemm256<<<gg, 256, 0, stream>>>(gat_out, dec_w + (size_t)lk * 65536, acc_buf, NNODE,
                                            gat_b + lk * 256, dec_b + lk * 256,
                                            0.01f, 1, 1, decays[k]);
        }
        ln_kernel<<<NNODE, 256, 0, stream>>>(acc_buf, h, ln_s + l * 256, ln_b + l * 256);
    }
}

// Round 4
// 1722.763 us; speedup vs baseline: 4.6540x; 4.6540x over previous
//
#include <hip/hip_runtime.h>
#include <hip/hip_bf16.h>

#define NNODE 50000
#define NEDGE 300000
#define KPAD 40

static const float DECAY0 = 1.0f;
static const float DECAY1 = 0.60653065971263342f;
static const float DECAY2 = 0.36787944117144233f;

typedef __attribute__((ext_vector_type(8))) short bf16x8;
typedef __attribute__((ext_vector_type(4))) float f32x4;

__device__ __forceinline__ void split_bf16(float f, unsigned short& hi, unsigned short& lo) {
    const unsigned u = __float_as_uint(f);
    hi = (unsigned short)(u >> 16);
    const float fh = __uint_as_float((unsigned)hi << 16);
    lo = (unsigned short)(__float_as_uint(f - fh) >> 16);
}

// ---------------- weight transpose: Wt[m][n][k] = W[m][k][n], 13 matrices of 256x256
__global__ __launch_bounds__(256) void transpose_w(
    const float* __restrict__ gat_w, const float* __restrict__ dec_w,
    const float* __restrict__ lin1_w, float* __restrict__ Wt)
{
    const int m = blockIdx.z;
    const float* src = (m < 6) ? gat_w + (size_t)m * 65536
                     : (m < 12) ? dec_w + (size_t)(m - 6) * 65536
                                : lin1_w;
    float* dst = Wt + (size_t)m * 65536;
    __shared__ float tile[32][33];
    const int bx = blockIdx.x * 32;   // n range
    const int by = blockIdx.y * 32;   // k range
    const int tx = threadIdx.x & 31;
    const int ty = threadIdx.x >> 5;  // 0..7
#pragma unroll
    for (int i = 0; i < 32; i += 8)
        tile[ty + i][tx] = src[(size_t)(by + ty + i) * 256 + bx + tx];  // tile[k][n]
    __syncthreads();
#pragma unroll
    for (int i = 0; i < 32; i += 8)
        dst[(size_t)(bx + ty + i) * 256 + by + tx] = tile[tx][ty + i];  // Wt[n][k]
}

// ---------------- MFMA GEMM (split bf16, 3 products): C[M,256] = ep((A+in_bias) @ W)
// Wt is [256(n)][256(k)] (pre-transposed). accum==0: C = decay*val ; 1: C += decay*val
__global__ __launch_bounds__(256) void gemm_mfma(
    const float* __restrict__ A, const float* __restrict__ Wt, float* __restrict__ C,
    int M, const float* __restrict__ in_bias, const float* __restrict__ out_bias,
    float slope, int do_act, int accum, float decay)
{
    __shared__ unsigned short Ah[128][KPAD];
    __shared__ unsigned short Al[128][KPAD];
    __shared__ unsigned short Bh[128][KPAD];
    __shared__ unsigned short Bl[128][KPAD];

    const int tid  = threadIdx.x;
    const int bm   = blockIdx.x * 128;
    const int bn   = blockIdx.y * 128;
    const int lane = tid & 63;
    const int w    = tid >> 6;
    const int wm   = w >> 1, wn = w & 1;
    const int srow = tid >> 1;             // staging row 0..127
    const int sks  = (tid & 1) << 4;       // staging k offset 0/16

    f32x4 acc[4][4];
#pragma unroll
    for (int mi = 0; mi < 4; mi++)
#pragma unroll
        for (int ni = 0; ni < 4; ni++) {
            acc[mi][ni][0] = 0.f; acc[mi][ni][1] = 0.f;
            acc[mi][ni][2] = 0.f; acc[mi][ni][3] = 0.f;
        }

    const int lrow = lane & 15;
    const int koff = (lane >> 4) << 3;

    for (int k0 = 0; k0 < 256; k0 += 32) {
        __syncthreads();
        // ---- stage A (with optional in_bias), split to hi/lo bf16
        {
            float v[16];
            const int gr = bm + srow;
            if (gr < M) {
                const float* ap = A + (size_t)gr * 256 + k0 + sks;
                const float4 f0 = ((const float4*)ap)[0];
                const float4 f1 = ((const float4*)ap)[1];
                const float4 f2 = ((const float4*)ap)[2];
                const float4 f3 = ((const float4*)ap)[3];
                v[0]=f0.x; v[1]=f0.y; v[2]=f0.z; v[3]=f0.w;
                v[4]=f1.x; v[5]=f1.y; v[6]=f1.z; v[7]=f1.w;
                v[8]=f2.x; v[9]=f2.y; v[10]=f2.z; v[11]=f2.w;
                v[12]=f3.x; v[13]=f3.y; v[14]=f3.z; v[15]=f3.w;
            } else {
#pragma unroll
                for (int j = 0; j < 16; j++) v[j] = 0.f;
            }
            if (in_bias) {
#pragma unroll
                for (int j = 0; j < 16; j++) v[j] += in_bias[k0 + sks + j];
            }
            bf16x8 h0, h1, l0, l1;
#pragma unroll
            for (int j = 0; j < 8; j++) {
                unsigned short h, l;
                split_bf16(v[j], h, l);
                h0[j] = (short)h; l0[j] = (short)l;
            }
#pragma unroll
            for (int j = 0; j < 8; j++) {
                unsigned short h, l;
                split_bf16(v[8 + j], h, l);
                h1[j] = (short)h; l1[j] = (short)l;
            }
            *(bf16x8*)&Ah[srow][sks]     = h0;
            *(bf16x8*)&Ah[srow][sks + 8] = h1;
            *(bf16x8*)&Al[srow][sks]     = l0;
            *(bf16x8*)&Al[srow][sks + 8] = l1;
        }
        // ---- stage B from Wt (row = output col n)
        {
            const float* bp = Wt + (size_t)(bn + srow) * 256 + k0 + sks;
            const float4 f0 = ((const float4*)bp)[0];
            const float4 f1 = ((const float4*)bp)[1];
            const float4 f2 = ((const float4*)bp)[2];
            const float4 f3 = ((const float4*)bp)[3];
            float v[16];
            v[0]=f0.x; v[1]=f0.y; v[2]=f0.z; v[3]=f0.w;
            v[4]=f1.x; v[5]=f1.y; v[6]=f1.z; v[7]=f1.w;
            v[8]=f2.x; v[9]=f2.y; v[10]=f2.z; v[11]=f2.w;
            v[12]=f3.x; v[13]=f3.y; v[14]=f3.z; v[15]=f3.w;
            bf16x8 h0, h1, l0, l1;
#pragma unroll
            for (int j = 0; j < 8; j++) {
                unsigned short h, l;
                split_bf16(v[j], h, l);
                h0[j] = (short)h; l0[j] = (short)l;
            }
#pragma unroll
            for (int j = 0; j < 8; j++) {
                unsigned short h, l;
                split_bf16(v[8 + j], h, l);
                h1[j] = (short)h; l1[j] = (short)l;
            }
            *(bf16x8*)&Bh[srow][sks]     = h0;
            *(bf16x8*)&Bh[srow][sks + 8] = h1;
            *(bf16x8*)&Bl[srow][sks]     = l0;
            *(bf16x8*)&Bl[srow][sks + 8] = l1;
        }
        __syncthreads();
        // ---- fragments + MFMA
        bf16x8 ah[4], al[4];
#pragma unroll
        for (int mi = 0; mi < 4; mi++) {
            const int r = 64 * wm + 16 * mi + lrow;
            ah[mi] = *(const bf16x8*)&Ah[r][koff];
            al[mi] = *(const bf16x8*)&Al[r][koff];
        }
#pragma unroll
        for (int ni = 0; ni < 4; ni++) {
            const int r = 64 * wn + 16 * ni + lrow;
            const bf16x8 bh = *(const bf16x8*)&Bh[r][koff];
            const bf16x8 bl = *(const bf16x8*)&Bl[r][koff];
#pragma unroll
            for (int mi = 0; mi < 4; mi++) {
                acc[mi][ni] = __builtin_amdgcn_mfma_f32_16x16x32_bf16(ah[mi], bh, acc[mi][ni], 0, 0, 0);
                acc[mi][ni] = __builtin_amdgcn_mfma_f32_16x16x32_bf16(al[mi], bh, acc[mi][ni], 0, 0, 0);
                acc[mi][ni] = __builtin_amdgcn_mfma_f32_16x16x32_bf16(ah[mi], bl, acc[mi][ni], 0, 0, 0);
            }
        }
    }

    // ---- epilogue: bias, leaky-relu, decay, (accumulate) store
    const int rb = bm + 64 * wm + ((lane >> 4) << 2);
    const int cb = bn + 64 * wn + (lane & 15);
#pragma unroll
    for (int ni = 0; ni < 4; ni++) {
        const int col = cb + 16 * ni;
        const float ob = out_bias ? out_bias[col] : 0.f;
#pragma unroll
        for (int mi = 0; mi < 4; mi++) {
#pragma unroll
            for (int r = 0; r < 4; r++) {
                const int row = rb + 16 * mi + r;
                if (row < M) {
                    float vv = acc[mi][ni][r] + ob;
                    if (do_act) vv = (vv > 0.f) ? vv : slope * vv;
                    vv *= decay;
                    float* cp = C + (size_t)row * 256 + col;
                    if (accum) *cp += vv; else *cp = vv;
                }
            }
        }
    }
}

// ---------------- alpha_s/alpha_d: [N,8] head-wise dot of hproj row with att vectors
__global__ __launch_bounds__(256) void alpha_kernel(
    const float* __restrict__ hproj, const float* __restrict__ att_s,
    const float* __restrict__ att_d, float* __restrict__ alpha_s, float* __restrict__ alpha_d)
{
    const int n = blockIdx.x;
    const int t = threadIdx.x;
    const float v  = hproj[(size_t)n * 256 + t];
    float ps = v * att_s[t];
    float pd = v * att_d[t];
#pragma unroll
    for (int off = 16; off > 0; off >>= 1) {
        ps += __shfl_xor(ps, off, 32);
        pd += __shfl_xor(pd, off, 32);
    }
    if ((t & 31) == 0) {
        alpha_s[n * 8 + (t >> 5)] = ps;
        alpha_d[n * 8 + (t >> 5)] = pd;
    }
}

// ---------------- CSR build: histogram of dst per hop
__global__ __launch_bounds__(256) void hist_kernel(
    const int* __restrict__ edges, int* __restrict__ hist)
{
    const int gid = blockIdx.x * 256 + threadIdx.x;
    if (gid >= 3 * NEDGE) return;
    const int k = gid / NEDGE;
    const int e = gid - k * NEDGE;
    const int d = edges[(size_t)k * 2 * NEDGE + NEDGE + e];
    atomicAdd(&hist[k * NNODE + d], 1);
}

// ---------------- exclusive scan per hop (one block of 1024 per hop)
__global__ __launch_bounds__(1024) void scan_kernel(
    const int* __restrict__ hist, int* __restrict__ row_ptr)
{
    const int hop = blockIdx.x;
    const int* hsrc = hist + hop * NNODE;
    int* rp = row_ptr + hop * (NNODE + 1);
    __shared__ int buf[1024];
    const int t = threadIdx.x;
    int offset = 0;
    for (int base = 0; base < NNODE; base += 1024) {
        const int idx = base + t;
        int v = (idx < NNODE) ? hsrc[idx] : 0;
        buf[t] = v;
        __syncthreads();
        for (int off = 1; off < 1024; off <<= 1) {
            int add = (t >= off) ? buf[t - off] : 0;
            __syncthreads();
            buf[t] += add;
            __syncthreads();
        }
        if (idx < NNODE) rp[idx] = offset + buf[t] - v;
        const int total = buf[1023];
        __syncthreads();
        offset += total;
    }
    if (t == 0) rp[NNODE] = offset;
}

// ---------------- copy row_ptr starts into cursor
__global__ __launch_bounds__(256) void cursor_kernel(
    const int* __restrict__ row_ptr, int* __restrict__ cursor)
{
    const int gid = blockIdx.x * 256 + threadIdx.x;
    if (gid >= 3 * NNODE) return;
    const int k = gid / NNODE;
    const int i = gid - k * NNODE;
    cursor[gid] = row_ptr[k * (NNODE + 1) + i];
}

// ---------------- fill CSR col (src ids) sorted by dst
__global__ __launch_bounds__(256) void fill_kernel(
    const int* __restrict__ edges, int* __restrict__ cursor, int* __restrict__ col)
{
    const int gid = blockIdx.x * 256 + threadIdx.x;
    if (gid >= 3 * NEDGE) return;
    const int k = gid / NEDGE;
    const int e = gid - k * NEDGE;
    const int s = edges[(size_t)k * 2 * NEDGE + e];
    const int d = edges[(size_t)k * 2 * NEDGE + NEDGE + e];
    const int pos = atomicAdd(&cursor[k * NNODE + d], 1);
    col[(size_t)k * NEDGE + pos] = s;
}

// ---------------- fused GAT aggregate: one wave per dst node, online softmax
__global__ __launch_bounds__(256) void gat_gather(
    const int* __restrict__ row_ptr, const int* __restrict__ col,
    const float* __restrict__ alpha_s, const float* __restrict__ alpha_d,
    const float* __restrict__ hproj, float* __restrict__ gat_out)
{
    const int wave = (blockIdx.x * 256 + threadIdx.x) >> 6;
    const int lane = threadIdx.x & 63;
    if (wave >= NNODE) return;
    const int d = wave;
    const int h = lane >> 3;                 // head for this lane's 4 elems
    const float adh = alpha_d[d * 8 + h];
    const int beg = row_ptr[d];
    const int end = row_ptr[d + 1];

    float m = -3.402823466e38f;
    float s = 0.f;
    float a0 = 0.f, a1 = 0.f, a2 = 0.f, a3 = 0.f;

    for (int e = beg; e < end; ++e) {
        const int sidx = col[e];
        float v = alpha_s[sidx * 8 + h] + adh;
        v = (v > 0.f) ? v : 0.2f * v;
        if (v > m) {
            const float f = __expf(m - v);   // 0 on first edge
            s *= f; a0 *= f; a1 *= f; a2 *= f; a3 *= f;
            m = v;
        }
        const float p = __expf(v - m);
        s += p;
        const float4 hv = *reinterpret_cast<const float4*>(hproj + (size_t)sidx * 256 + lane * 4);
        a0 += p * hv.x; a1 += p * hv.y; a2 += p * hv.z; a3 += p * hv.w;
    }
    const float inv = 1.f / (s + 1e-16f);
    *reinterpret_cast<float4*>(gat_out + (size_t)d * 256 + lane * 4) =
        make_float4(a0 * inv, a1 * inv, a2 * inv, a3 * inv);
}

// ---------------- LayerNorm + residual (in-place on h)
__global__ __launch_bounds__(256) void ln_kernel(
    const float* __restrict__ accb, float* __restrict__ h,
    const float* __restrict__ lns, const float* __restrict__ lnb)
{
    const int n = blockIdx.x;
    const int t = threadIdx.x;
    const float a = accb[(size_t)n * 256 + t];
    __shared__ float red[256];
    red[t] = a;
    __syncthreads();
    for (int off = 128; off > 0; off >>= 1) {
        if (t < off) red[t] += red[t + off];
        __syncthreads();
    }
    const float mu = red[0] * (1.f / 256.f);
    __syncthreads();
    const float dv = a - mu;
    red[t] = dv * dv;
    __syncthreads();
    for (int off = 128; off > 0; off >>= 1) {
        if (t < off) red[t] += red[t + off];
        __syncthreads();
    }
    const float var = red[0] * (1.f / 256.f);
    const float r = rsqrtf(var + 1e-5f);
    const size_t idx = (size_t)n * 256 + t;
    h[idx] = dv * r * lns[t] + lnb[t] + h[idx];
}

extern "C" void kernel_launch(void* const* d_in, const int* in_sizes, int n_in,
                              void* d_out, int out_size, void* d_ws, size_t ws_size,
                              hipStream_t stream) {
    const float* x      = (const float*)d_in[0];
    const int*   edges  = (const int*)  d_in[1];
    const float* lin1_w = (const float*)d_in[2];
    const float* lin1_b = (const float*)d_in[3];
    const float* gat_w  = (const float*)d_in[4];
    const float* att_s  = (const float*)d_in[5];
    const float* att_d  = (const float*)d_in[6];
    const float* gat_b  = (const float*)d_in[7];
    const float* dec_w  = (const float*)d_in[8];
    const float* dec_b  = (const float*)d_in[9];
    const float* ln_s   = (const float*)d_in[10];
    const float* ln_b   = (const float*)d_in[11];

    float* h = (float*)d_out;              // current node features live in d_out
    const size_t NF = (size_t)NNODE * 256;
    const size_t N8 = (size_t)NNODE * 8;

    float* acc_buf = (float*)d_ws;
    float* hproj   = acc_buf + NF;
    float* gat_out = hproj + NF;
    float* as_     = gat_out + NF;
    float* ad_     = as_ + N8;
    int*   hist    = (int*)(ad_ + N8);           // [3][N]
    int*   cursor  = hist + 3 * NNODE;           // [3][N]
    int*   row_ptr = cursor + 3 * NNODE;         // [3][N+1]
    int*   col     = row_ptr + 3 * (NNODE + 1);  // [3][E]
    float* Wt      = (float*)(col + 3 * NEDGE);  // [13][256][256] transposed weights

    const float decays[3] = {DECAY0, DECAY1, DECAY2};

    dim3 gg((NNODE + 127) / 128, 2);
    dim3 tg(8, 8, 13);
    const int e3b = (3 * NEDGE + 255) / 256;
    const int n3b = (3 * NNODE + 255) / 256;
    const int gb  = (NNODE * 64 + 255) / 256;

    // ---- weight transpose (Wt[n][k]) for MFMA B staging
    transpose_w<<<tg, 256, 0, stream>>>(gat_w, dec_w, lin1_w, Wt);

    // ---- CSR build (edges shared across layers; 3 hops)
    hipMemsetAsync(hist, 0, 3 * NNODE * sizeof(int), stream);
    hist_kernel<<<e3b, 256, 0, stream>>>(edges, hist);
    scan_kernel<<<3, 1024, 0, stream>>>(hist, row_ptr);
    cursor_kernel<<<n3b, 256, 0, stream>>>(row_ptr, cursor);
    fill_kernel<<<e3b, 256, 0, stream>>>(edges, cursor, col);

    // h = leaky_relu(x @ lin1_w + lin1_b, 0.01)
    gemm_mfma<<<gg, 256, 0, stream>>>(x, Wt + (size_t)12 * 65536, h, NNODE,
                                      nullptr, lin1_b, 0.01f, 1, 0, 1.f);

    for (int l = 0; l < 2; l++) {
        for (int k = 0; k < 3; k++) {
            const int lk = l * 3 + k;
            // hproj = h @ gat_w[l,k]
            gemm_mfma<<<gg, 256, 0, stream>>>(h, Wt + (size_t)lk * 65536, hproj, NNODE,
                                              nullptr, nullptr, 0.f, 0, 0, 1.f);
            // per-node attention logits
            alpha_kernel<<<NNODE, 256, 0, stream>>>(hproj, att_s + lk * 256, att_d + lk * 256,
                                                    as_, ad_);
            // fused segment-softmax + weighted gather (no atomics)
            gat_gather<<<gb, 256, 0, stream>>>(row_ptr + (size_t)k * (NNODE + 1),
                                               col + (size_t)k * NEDGE,
                                               as_, ad_, hproj, gat_out);
            // acc (+)= decay[k] * lrelu((gat_out + gat_bias) @ dec_w + dec_b, 0.01)
            gemm_mfma<<<gg, 256, 0, stream>>>(gat_out, Wt + (size_t)(6 + lk) * 65536, acc_buf,
                                              NNODE, gat_b + lk * 256, dec_b + lk * 256,
                                              0.01f, 1, (k > 0) ? 1 : 0, decays[k]);
        }
        ln_kernel<<<NNODE, 256, 0, stream>>>(acc_buf, h, ln_s + l * 256, ln_b + l * 256);
    }
}

// Round 7
// 1685.913 us; speedup vs baseline: 4.7557x; 1.0219x over previous
//
#include <hip/hip_runtime.h>
#include <hip/hip_bf16.h>

#define NNODE 50000
#define NEDGE 300000
#define KPAD 40

static const float DECAY0 = 1.0f;
static const float DECAY1 = 0.60653065971263342f;
static const float DECAY2 = 0.36787944117144233f;

typedef __attribute__((ext_vector_type(8))) short bf16x8;
typedef __attribute__((ext_vector_type(4))) float f32x4;
typedef __attribute__((ext_vector_type(4))) unsigned short u16x4;

// returns lo in bits[15:0], hi in bits[31:16]
__device__ __forceinline__ unsigned split2(float f) {
    const unsigned u = __float_as_uint(f);
    const unsigned hi = u >> 16;
    const float fh = __uint_as_float(hi << 16);
    const unsigned lo = __float_as_uint(f - fh) >> 16;
    return (hi << 16) | lo;
}
__device__ __forceinline__ float bf2f(unsigned short u) {
    return __uint_as_float((unsigned)u << 16);
}

// ---------------- weight transpose+split: Wp[m][n][0..255]=hi(W[k][n]), [256..511]=lo
__global__ __launch_bounds__(256) void transpose_split_w(
    const float* __restrict__ gat_w, const float* __restrict__ dec_w,
    const float* __restrict__ lin1_w, unsigned short* __restrict__ Wp)
{
    const int m = blockIdx.z;
    const float* src = (m < 6) ? gat_w + (size_t)m * 65536
                     : (m < 12) ? dec_w + (size_t)(m - 6) * 65536
                                : lin1_w;
    unsigned short* dst = Wp + (size_t)m * 131072;
    __shared__ float tile[32][33];
    const int bx = blockIdx.x * 32;   // n range
    const int by = blockIdx.y * 32;   // k range
    const int tx = threadIdx.x & 31;
    const int ty = threadIdx.x >> 5;  // 0..7
#pragma unroll
    for (int i = 0; i < 32; i += 8)
        tile[ty + i][tx] = src[(size_t)(by + ty + i) * 256 + bx + tx];  // tile[k][n]
    __syncthreads();
#pragma unroll
    for (int i = 0; i < 32; i += 8) {
        const int n = bx + ty + i, k = by + tx;
        const unsigned p = split2(tile[tx][ty + i]);
        dst[(size_t)n * 512 + k] = (unsigned short)(p >> 16);
        dst[(size_t)n * 512 + 256 + k] = (unsigned short)(p & 0xffffu);
    }
}

// ---------------- fp32 [N][256] -> packed split bf16 [N][512]
__global__ __launch_bounds__(256) void convert_split(
    const float* __restrict__ src, unsigned short* __restrict__ dst)
{
    const int gid = blockIdx.x * 256 + threadIdx.x;   // one per 8 elems
    if (gid >= NNODE * 32) return;
    const int row = gid >> 5;
    const int k = (gid & 31) * 8;
    const float4 f0 = *reinterpret_cast<const float4*>(src + (size_t)row * 256 + k);
    const float4 f1 = *reinterpret_cast<const float4*>(src + (size_t)row * 256 + k + 4);
    u16x4 h0, h1, l0, l1;
    unsigned p;
    p = split2(f0.x); h0[0] = (unsigned short)(p >> 16); l0[0] = (unsigned short)p;
    p = split2(f0.y); h0[1] = (unsigned short)(p >> 16); l0[1] = (unsigned short)p;
    p = split2(f0.z); h0[2] = (unsigned short)(p >> 16); l0[2] = (unsigned short)p;
    p = split2(f0.w); h0[3] = (unsigned short)(p >> 16); l0[3] = (unsigned short)p;
    p = split2(f1.x); h1[0] = (unsigned short)(p >> 16); l1[0] = (unsigned short)p;
    p = split2(f1.y); h1[1] = (unsigned short)(p >> 16); l1[1] = (unsigned short)p;
    p = split2(f1.z); h1[2] = (unsigned short)(p >> 16); l1[2] = (unsigned short)p;
    p = split2(f1.w); h1[3] = (unsigned short)(p >> 16); l1[3] = (unsigned short)p;
    unsigned short* dh = dst + (size_t)row * 512 + k;
    *(u16x4*)dh = h0; *(u16x4*)(dh + 4) = h1;
    *(u16x4*)(dh + 256) = l0; *(u16x4*)(dh + 260) = l1;
}

// ---------------- MFMA GEMM on pre-split operands, 2-phase reg prefetch
// Ap: [M][512] (hi|lo), Wp: [256][512]. If Cpack!=null: split-write output; else C fp32.
__global__ __launch_bounds__(256) void gemm_pack(
    const unsigned short* __restrict__ Ap, const unsigned short* __restrict__ Wp,
    float* __restrict__ C, unsigned short* __restrict__ Cpack,
    int M, const float* __restrict__ out_bias,
    float slope, int do_act, int accum, float decay)
{
    __shared__ unsigned short Ah[128][KPAD];
    __shared__ unsigned short Al[128][KPAD];
    __shared__ unsigned short Bh[128][KPAD];
    __shared__ unsigned short Bl[128][KPAD];

    const int tid  = threadIdx.x;
    const int bm   = blockIdx.x * 128;
    const int bn   = blockIdx.y * 128;
    const int lane = tid & 63;
    const int w    = tid >> 6;
    const int wm   = w >> 1, wn = w & 1;
    const int srow = tid >> 1;             // staging row 0..127
    const int skb  = (tid & 1) << 4;       // staging k offset 0/16

    const bool aval = (bm + srow) < M;
    const unsigned short* ap = Ap + (size_t)(bm + srow) * 512 + skb;
    const unsigned short* bp = Wp + (size_t)(bn + srow) * 512 + skb;

    bf16x8 rAh0 = {0,0,0,0,0,0,0,0}, rAh1 = rAh0, rAl0 = rAh0, rAl1 = rAh0;
    bf16x8 rBh0, rBh1, rBl0, rBl1;

#define LOADT(K0)                                                        \
    do {                                                                 \
        if (aval) {                                                      \
            rAh0 = *(const bf16x8*)(ap + (K0));                          \
            rAh1 = *(const bf16x8*)(ap + (K0) + 8);                      \
            rAl0 = *(const bf16x8*)(ap + 256 + (K0));                    \
            rAl1 = *(const bf16x8*)(ap + 256 + (K0) + 8);                \
        }                                                                \
        rBh0 = *(const bf16x8*)(bp + (K0));                              \
        rBh1 = *(const bf16x8*)(bp + (K0) + 8);                          \
        rBl0 = *(const bf16x8*)(bp + 256 + (K0));                        \
        rBl1 = *(const bf16x8*)(bp + 256 + (K0) + 8);                    \
    } while (0)

    f32x4 acc[4][4];
#pragma unroll
    for (int mi = 0; mi < 4; mi++)
#pragma unroll
        for (int ni = 0; ni < 4; ni++) {
            acc[mi][ni][0] = 0.f; acc[mi][ni][1] = 0.f;
            acc[mi][ni][2] = 0.f; acc[mi][ni][3] = 0.f;
        }

    const int lrow = lane & 15;
    const int koff = (lane >> 4) << 3;

    LOADT(0);

    for (int kt = 0; kt < 8; kt++) {
        __syncthreads();
        *(bf16x8*)&Ah[srow][skb]     = rAh0;
        *(bf16x8*)&Ah[srow][skb + 8] = rAh1;
        *(bf16x8*)&Al[srow][skb]     = rAl0;
        *(bf16x8*)&Al[srow][skb + 8] = rAl1;
        *(bf16x8*)&Bh[srow][skb]     = rBh0;
        *(bf16x8*)&Bh[srow][skb + 8] = rBh1;
        *(bf16x8*)&Bl[srow][skb]     = rBl0;
        *(bf16x8*)&Bl[srow][skb + 8] = rBl1;
        __syncthreads();
        if (kt < 7) LOADT((kt + 1) * 32);   // prefetch next tile; lands during MFMA

        bf16x8 fah[4], fal[4];
#pragma unroll
        for (int mi = 0; mi < 4; mi++) {
            const int r = 64 * wm + 16 * mi + lrow;
            fah[mi] = *(const bf16x8*)&Ah[r][koff];
            fal[mi] = *(const bf16x8*)&Al[r][koff];
        }
#pragma unroll
        for (int ni = 0; ni < 4; ni++) {
            const int r = 64 * wn + 16 * ni + lrow;
            const bf16x8 fbh = *(const bf16x8*)&Bh[r][koff];
            const bf16x8 fbl = *(const bf16x8*)&Bl[r][koff];
#pragma unroll
            for (int mi = 0; mi < 4; mi++) {
                acc[mi][ni] = __builtin_amdgcn_mfma_f32_16x16x32_bf16(fah[mi], fbh, acc[mi][ni], 0, 0, 0);
                acc[mi][ni] = __builtin_amdgcn_mfma_f32_16x16x32_bf16(fal[mi], fbh, acc[mi][ni], 0, 0, 0);
                acc[mi][ni] = __builtin_amdgcn_mfma_f32_16x16x32_bf16(fah[mi], fbl, acc[mi][ni], 0, 0, 0);
            }
        }
    }
#undef LOADT

    // ---- epilogue
    const int rb = bm + 64 * wm + ((lane >> 4) << 2);
    const int cb = bn + 64 * wn + (lane & 15);
#pragma unroll
    for (int ni = 0; ni < 4; ni++) {
        const int col = cb + 16 * ni;
        const float ob = out_bias ? out_bias[col] : 0.f;
#pragma unroll
        for (int mi = 0; mi < 4; mi++) {
#pragma unroll
            for (int r = 0; r < 4; r++) {
                const int row = rb + 16 * mi + r;
                if (row < M) {
                    float vv = acc[mi][ni][r] + ob;
                    if (do_act) vv = (vv > 0.f) ? vv : slope * vv;
                    vv *= decay;
                    if (Cpack) {
                        const unsigned p = split2(vv);
                        Cpack[(size_t)row * 512 + col] = (unsigned short)(p >> 16);
                        Cpack[(size_t)row * 512 + 256 + col] = (unsigned short)(p & 0xffffu);
                    } else if (accum) {
                        C[(size_t)row * 256 + col] += vv;
                    } else {
                        C[(size_t)row * 256 + col] = vv;
                    }
                }
            }
        }
    }
}

// ---------------- alpha_s/alpha_d: [N,8] head-wise dot of hproj row with att vectors
__global__ __launch_bounds__(256) void alpha_kernel(
    const float* __restrict__ hproj, const float* __restrict__ att_s,
    const float* __restrict__ att_d, float* __restrict__ alpha_s, float* __restrict__ alpha_d)
{
    const int n = blockIdx.x;
    const int t = threadIdx.x;
    const float v  = hproj[(size_t)n * 256 + t];
    float ps = v * att_s[t];
    float pd = v * att_d[t];
#pragma unroll
    for (int off = 16; off > 0; off >>= 1) {
        ps += __shfl_xor(ps, off, 32);
        pd += __shfl_xor(pd, off, 32);
    }
    if ((t & 31) == 0) {
        alpha_s[n * 8 + (t >> 5)] = ps;
        alpha_d[n * 8 + (t >> 5)] = pd;
    }
}

// ---------------- CSR build
__global__ __launch_bounds__(256) void hist_kernel(
    const int* __restrict__ edges, int* __restrict__ hist)
{
    const int gid = blockIdx.x * 256 + threadIdx.x;
    if (gid >= 3 * NEDGE) return;
    const int k = gid / NEDGE;
    const int e = gid - k * NEDGE;
    const int d = edges[(size_t)k * 2 * NEDGE + NEDGE + e];
    atomicAdd(&hist[k * NNODE + d], 1);
}

__global__ __launch_bounds__(1024) void scan_kernel(
    const int* __restrict__ hist, int* __restrict__ row_ptr)
{
    const int hop = blockIdx.x;
    const int* hsrc = hist + hop * NNODE;
    int* rp = row_ptr + hop * (NNODE + 1);
    __shared__ int buf[1024];
    const int t = threadIdx.x;
    int offset = 0;
    for (int base = 0; base < NNODE; base += 1024) {
        const int idx = base + t;
        int v = (idx < NNODE) ? hsrc[idx] : 0;
        buf[t] = v;
        __syncthreads();
        for (int off = 1; off < 1024; off <<= 1) {
            int add = (t >= off) ? buf[t - off] : 0;
            __syncthreads();
            buf[t] += add;
            __syncthreads();
        }
        if (idx < NNODE) rp[idx] = offset + buf[t] - v;
        const int total = buf[1023];
        __syncthreads();
        offset += total;
    }
    if (t == 0) rp[NNODE] = offset;
}

__global__ __launch_bounds__(256) void cursor_kernel(
    const int* __restrict__ row_ptr, int* __restrict__ cursor)
{
    const int gid = blockIdx.x * 256 + threadIdx.x;
    if (gid >= 3 * NNODE) return;
    const int k = gid / NNODE;
    const int i = gid - k * NNODE;
    cursor[gid] = row_ptr[k * (NNODE + 1) + i];
}

__global__ __launch_bounds__(256) void fill_kernel(
    const int* __restrict__ edges, int* __restrict__ cursor, int* __restrict__ col)
{
    const int gid = blockIdx.x * 256 + threadIdx.x;
    if (gid >= 3 * NEDGE) return;
    const int k = gid / NEDGE;
    const int e = gid - k * NEDGE;
    const int s = edges[(size_t)k * 2 * NEDGE + e];
    const int d = edges[(size_t)k * 2 * NEDGE + NEDGE + e];
    const int pos = atomicAdd(&cursor[k * NNODE + d], 1);
    col[(size_t)k * NEDGE + pos] = s;
}

// ---------------- fused GAT aggregate: one wave per dst, online softmax,
// epilogue adds gat_bias and writes split-pack bf16 (ready for dec GEMM)
__global__ __launch_bounds__(256) void gat_gather(
    const int* __restrict__ row_ptr, const int* __restrict__ col,
    const float* __restrict__ alpha_s, const float* __restrict__ alpha_d,
    const float* __restrict__ hproj, const float* __restrict__ bias,
    unsigned short* __restrict__ outp)
{
    const int wave = (blockIdx.x * 256 + threadIdx.x) >> 6;
    const int lane = threadIdx.x & 63;
    if (wave >= NNODE) return;
    const int d = wave;
    const int h = lane >> 3;
    const float adh = alpha_d[d * 8 + h];
    const int beg = row_ptr[d];
    const int end = row_ptr[d + 1];

    float m = -3.402823466e38f;
    float s = 0.f;
    float a0 = 0.f, a1 = 0.f, a2 = 0.f, a3 = 0.f;

    for (int e = beg; e < end; ++e) {
        const int sidx = col[e];
        float v = alpha_s[sidx * 8 + h] + adh;
        v = (v > 0.f) ? v : 0.2f * v;
        if (v > m) {
            const float f = __expf(m - v);
            s *= f; a0 *= f; a1 *= f; a2 *= f; a3 *= f;
            m = v;
        }
        const float p = __expf(v - m);
        s += p;
        const float4 hv = *reinterpret_cast<const float4*>(hproj + (size_t)sidx * 256 + lane * 4);
        a0 += p * hv.x; a1 += p * hv.y; a2 += p * hv.z; a3 += p * hv.w;
    }
    const float inv = 1.f / (s + 1e-16f);
    const float b0 = bias[lane * 4 + 0], b1 = bias[lane * 4 + 1];
    const float b2 = bias[lane * 4 + 2], b3 = bias[lane * 4 + 3];
    u16x4 hi, lo;
    unsigned p0 = split2(a0 * inv + b0);
    unsigned p1 = split2(a1 * inv + b1);
    unsigned p2 = split2(a2 * inv + b2);
    unsigned p3 = split2(a3 * inv + b3);
    hi[0] = (unsigned short)(p0 >> 16); lo[0] = (unsigned short)p0;
    hi[1] = (unsigned short)(p1 >> 16); lo[1] = (unsigned short)p1;
    hi[2] = (unsigned short)(p2 >> 16); lo[2] = (unsigned short)p2;
    hi[3] = (unsigned short)(p3 >> 16); lo[3] = (unsigned short)p3;
    *(u16x4*)(outp + (size_t)d * 512 + lane * 4) = hi;
    *(u16x4*)(outp + (size_t)d * 512 + 256 + lane * 4) = lo;
}

// ---------------- LayerNorm + residual; residual read from split-pack;
// writes split-pack (intermediate layer) or fp32 final output
__global__ __launch_bounds__(256) void ln_kernel(
    const float* __restrict__ accb, const unsigned short* __restrict__ hres,
    unsigned short* __restrict__ hout, float* __restrict__ final_out,
    const float* __restrict__ lns, const float* __restrict__ lnb)
{
    const int n = blockIdx.x;
    const int t = threadIdx.x;
    const float a = accb[(size_t)n * 256 + t];
    __shared__ float red[256];
    red[t] = a;
    __syncthreads();
    for (int off = 128; off > 0; off >>= 1) {
        if (t < off) red[t] += red[t + off];
        __syncthreads();
    }
    const float mu = red[0] * (1.f / 256.f);
    __syncthreads();
    const float dv = a - mu;
    red[t] = dv * dv;
    __syncthreads();
    for (int off = 128; off > 0; off >>= 1) {
        if (t < off) red[t] += red[t + off];
        __syncthreads();
    }
    const float var = red[0] * (1.f / 256.f);
    const float r = rsqrtf(var + 1e-5f);
    const float res = bf2f(hres[(size_t)n * 512 + t]) + bf2f(hres[(size_t)n * 512 + 256 + t]);
    const float o = dv * r * lns[t] + lnb[t] + res;
    if (final_out) {
        final_out[(size_t)n * 256 + t] = o;
    } else {
        const unsigned p = split2(o);
        hout[(size_t)n * 512 + t] = (unsigned short)(p >> 16);
        hout[(size_t)n * 512 + 256 + t] = (unsigned short)(p & 0xffffu);
    }
}

extern "C" void kernel_launch(void* const* d_in, const int* in_sizes, int n_in,
                              void* d_out, int out_size, void* d_ws, size_t ws_size,
                              hipStream_t stream) {
    const float* x      = (const float*)d_in[0];
    const int*   edges  = (const int*)  d_in[1];
    const float* lin1_w = (const float*)d_in[2];
    const float* lin1_b = (const float*)d_in[3];
    const float* gat_w  = (const float*)d_in[4];
    const float* att_s  = (const float*)d_in[5];
    const float* att_d  = (const float*)d_in[6];
    const float* gat_b  = (const float*)d_in[7];
    const float* dec_w  = (const float*)d_in[8];
    const float* dec_b  = (const float*)d_in[9];
    const float* ln_s   = (const float*)d_in[10];
    const float* ln_b   = (const float*)d_in[11];

    float* out = (float*)d_out;
    const size_t NF = (size_t)NNODE * 256;
    const size_t NP = (size_t)NNODE * 512;
    const size_t N8 = (size_t)NNODE * 8;

    float*          acc_buf = (float*)d_ws;
    float*          hproj   = acc_buf + NF;
    unsigned short* gpack   = (unsigned short*)(hproj + NF);  // x-pack, then gat_out-pack
    unsigned short* hpack   = gpack + NP;
    unsigned short* wpack   = hpack + NP;                     // [13][256][512]
    float*          as_     = (float*)(wpack + (size_t)13 * 131072);
    float*          ad_     = as_ + N8;
    int*            hist    = (int*)(ad_ + N8);
    int*            cursor  = hist + 3 * NNODE;
    int*            row_ptr = cursor + 3 * NNODE;
    int*            col     = row_ptr + 3 * (NNODE + 1);

    const float decays[3] = {DECAY0, DECAY1, DECAY2};

    dim3 gg((NNODE + 127) / 128, 2);
    dim3 tg(8, 8, 13);
    const int e3b = (3 * NEDGE + 255) / 256;
    const int n3b = (3 * NNODE + 255) / 256;
    const int gb  = (NNODE * 64 + 255) / 256;
    const int cvb = (NNODE * 32 + 255) / 256;

    transpose_split_w<<<tg, 256, 0, stream>>>(gat_w, dec_w, lin1_w, wpack);
    convert_split<<<cvb, 256, 0, stream>>>(x, gpack);

    (void)hipMemsetAsync(hist, 0, 3 * NNODE * sizeof(int), stream);
    hist_kernel<<<e3b, 256, 0, stream>>>(edges, hist);
    scan_kernel<<<3, 1024, 0, stream>>>(hist, row_ptr);
    cursor_kernel<<<n3b, 256, 0, stream>>>(row_ptr, cursor);
    fill_kernel<<<e3b, 256, 0, stream>>>(edges, cursor, col);

    // hpack = split(leaky_relu(x @ lin1_w + lin1_b))
    gemm_pack<<<gg, 256, 0, stream>>>(gpack, wpack + (size_t)12 * 131072, nullptr, hpack,
                                      NNODE, lin1_b, 0.01f, 1, 0, 1.f);

    for (int l = 0; l < 2; l++) {
        for (int k = 0; k < 3; k++) {
            const int lk = l * 3 + k;
            // hproj = h @ gat_w[l,k]  (fp32 out)
            gemm_pack<<<gg, 256, 0, stream>>>(hpack, wpack + (size_t)lk * 131072, hproj, nullptr,
                                              NNODE, nullptr, 0.f, 0, 0, 1.f);
            alpha_kernel<<<NNODE, 256, 0, stream>>>(hproj, att_s + lk * 256, att_d + lk * 256,
                                                    as_, ad_);
            // gpack = split(gat_aggregate + gat_bias)
            gat_gather<<<gb, 256, 0, stream>>>(row_ptr + (size_t)k * (NNODE + 1),
                                               col + (size_t)k * NEDGE,
                                               as_, ad_, hproj, gat_b + lk * 256, gpack);
            // acc (+)= decay[k] * lrelu(gpack @ dec_w + dec_b)
            gemm_pack<<<gg, 256, 0, stream>>>(gpack, wpack + (size_t)(6 + lk) * 131072, acc_buf,
                                              nullptr, NNODE, dec_b + lk * 256,
                                              0.01f, 1, (k > 0) ? 1 : 0, decays[k]);
        }
        ln_kernel<<<NNODE, 256, 0, stream>>>(acc_buf, hpack, hpack,
                                             (l == 1) ? out : nullptr,
                                             ln_s + l * 256, ln_b + l * 256);
    }
}

// Round 8
// 1500.946 us; speedup vs baseline: 5.3418x; 1.1232x over previous
//
#include <hip/hip_runtime.h>
#include <hip/hip_bf16.h>

#define NNODE 50000
#define NEDGE 300000
#define KPAD 40

static const float DECAY0 = 1.0f;
static const float DECAY1 = 0.60653065971263342f;
static const float DECAY2 = 0.36787944117144233f;

typedef __attribute__((ext_vector_type(8))) short bf16x8;
typedef __attribute__((ext_vector_type(4))) float f32x4;
typedef __attribute__((ext_vector_type(4))) unsigned short u16x4;

// returns lo in bits[15:0], hi in bits[31:16]  (truncation split, hi+lo == f exactly-ish)
__device__ __forceinline__ unsigned split2(float f) {
    const unsigned u = __float_as_uint(f);
    const unsigned hi = u >> 16;
    const float fh = __uint_as_float(hi << 16);
    const unsigned lo = __float_as_uint(f - fh) >> 16;
    return (hi << 16) | lo;
}
__device__ __forceinline__ float bf2f(unsigned short u) {
    return __uint_as_float((unsigned)u << 16);
}
// round-to-nearest-even bf16
__device__ __forceinline__ unsigned short rn_bf16(float f) {
    const unsigned u = __float_as_uint(f);
    return (unsigned short)((u + 0x7fffu + ((u >> 16) & 1u)) >> 16);
}

// ---------------- weight transpose+split: Wp[m][n][0..255]=hi(W[k][n]), [256..511]=lo
__global__ __launch_bounds__(256) void transpose_split_w(
    const float* __restrict__ gat_w, const float* __restrict__ dec_w,
    const float* __restrict__ lin1_w, unsigned short* __restrict__ Wp)
{
    const int m = blockIdx.z;
    const float* src = (m < 6) ? gat_w + (size_t)m * 65536
                     : (m < 12) ? dec_w + (size_t)(m - 6) * 65536
                                : lin1_w;
    unsigned short* dst = Wp + (size_t)m * 131072;
    __shared__ float tile[32][33];
    const int bx = blockIdx.x * 32;   // n range
    const int by = blockIdx.y * 32;   // k range
    const int tx = threadIdx.x & 31;
    const int ty = threadIdx.x >> 5;  // 0..7
#pragma unroll
    for (int i = 0; i < 32; i += 8)
        tile[ty + i][tx] = src[(size_t)(by + ty + i) * 256 + bx + tx];  // tile[k][n]
    __syncthreads();
#pragma unroll
    for (int i = 0; i < 32; i += 8) {
        const int n = bx + ty + i, k = by + tx;
        const unsigned p = split2(tile[tx][ty + i]);
        dst[(size_t)n * 512 + k] = (unsigned short)(p >> 16);
        dst[(size_t)n * 512 + 256 + k] = (unsigned short)(p & 0xffffu);
    }
}

// ---------------- fp32 [N][256] -> packed split bf16 [N][512]
__global__ __launch_bounds__(256) void convert_split(
    const float* __restrict__ src, unsigned short* __restrict__ dst)
{
    const int gid = blockIdx.x * 256 + threadIdx.x;   // one per 8 elems
    if (gid >= NNODE * 32) return;
    const int row = gid >> 5;
    const int k = (gid & 31) * 8;
    const float4 f0 = *reinterpret_cast<const float4*>(src + (size_t)row * 256 + k);
    const float4 f1 = *reinterpret_cast<const float4*>(src + (size_t)row * 256 + k + 4);
    u16x4 h0, h1, l0, l1;
    unsigned p;
    p = split2(f0.x); h0[0] = (unsigned short)(p >> 16); l0[0] = (unsigned short)p;
    p = split2(f0.y); h0[1] = (unsigned short)(p >> 16); l0[1] = (unsigned short)p;
    p = split2(f0.z); h0[2] = (unsigned short)(p >> 16); l0[2] = (unsigned short)p;
    p = split2(f0.w); h0[3] = (unsigned short)(p >> 16); l0[3] = (unsigned short)p;
    p = split2(f1.x); h1[0] = (unsigned short)(p >> 16); l1[0] = (unsigned short)p;
    p = split2(f1.y); h1[1] = (unsigned short)(p >> 16); l1[1] = (unsigned short)p;
    p = split2(f1.z); h1[2] = (unsigned short)(p >> 16); l1[2] = (unsigned short)p;
    p = split2(f1.w); h1[3] = (unsigned short)(p >> 16); l1[3] = (unsigned short)p;
    unsigned short* dh = dst + (size_t)row * 512 + k;
    *(u16x4*)dh = h0; *(u16x4*)(dh + 4) = h1;
    *(u16x4*)(dh + 256) = l0; *(u16x4*)(dh + 260) = l1;
}

// ---------------- MFMA GEMM on pre-split operands, 2-phase reg prefetch
// Ap: [M][512] (hi|lo), Wp: [256][512].
// Output modes: payload!=null -> bf16-RN [M][256] (no bias/act);
//               Cpack!=null  -> split hi/lo [M][512] with bias/act;
//               else         -> fp32 C with bias/act/decay/accum.
__global__ __launch_bounds__(256) void gemm_pack(
    const unsigned short* __restrict__ Ap, const unsigned short* __restrict__ Wp,
    float* __restrict__ C, unsigned short* __restrict__ Cpack,
    unsigned short* __restrict__ payload,
    int M, const float* __restrict__ out_bias,
    float slope, int do_act, int accum, float decay)
{
    __shared__ unsigned short Ah[128][KPAD];
    __shared__ unsigned short Al[128][KPAD];
    __shared__ unsigned short Bh[128][KPAD];
    __shared__ unsigned short Bl[128][KPAD];

    const int tid  = threadIdx.x;
    const int bm   = blockIdx.x * 128;
    const int bn   = blockIdx.y * 128;
    const int lane = tid & 63;
    const int w    = tid >> 6;
    const int wm   = w >> 1, wn = w & 1;
    const int srow = tid >> 1;             // staging row 0..127
    const int skb  = (tid & 1) << 4;       // staging k offset 0/16

    const bool aval = (bm + srow) < M;
    const unsigned short* ap = Ap + (size_t)(bm + srow) * 512 + skb;
    const unsigned short* bp = Wp + (size_t)(bn + srow) * 512 + skb;

    bf16x8 rAh0 = {0,0,0,0,0,0,0,0}, rAh1 = rAh0, rAl0 = rAh0, rAl1 = rAh0;
    bf16x8 rBh0, rBh1, rBl0, rBl1;

#define LOADT(K0)                                                        \
    do {                                                                 \
        if (aval) {                                                      \
            rAh0 = *(const bf16x8*)(ap + (K0));                          \
            rAh1 = *(const bf16x8*)(ap + (K0) + 8);                      \
            rAl0 = *(const bf16x8*)(ap + 256 + (K0));                    \
            rAl1 = *(const bf16x8*)(ap + 256 + (K0) + 8);                \
        }                                                                \
        rBh0 = *(const bf16x8*)(bp + (K0));                              \
        rBh1 = *(const bf16x8*)(bp + (K0) + 8);                          \
        rBl0 = *(const bf16x8*)(bp + 256 + (K0));                        \
        rBl1 = *(const bf16x8*)(bp + 256 + (K0) + 8);                    \
    } while (0)

    f32x4 acc[4][4];
#pragma unroll
    for (int mi = 0; mi < 4; mi++)
#pragma unroll
        for (int ni = 0; ni < 4; ni++) {
            acc[mi][ni][0] = 0.f; acc[mi][ni][1] = 0.f;
            acc[mi][ni][2] = 0.f; acc[mi][ni][3] = 0.f;
        }

    const int lrow = lane & 15;
    const int koff = (lane >> 4) << 3;

    LOADT(0);

    for (int kt = 0; kt < 8; kt++) {
        __syncthreads();
        *(bf16x8*)&Ah[srow][skb]     = rAh0;
        *(bf16x8*)&Ah[srow][skb + 8] = rAh1;
        *(bf16x8*)&Al[srow][skb]     = rAl0;
        *(bf16x8*)&Al[srow][skb + 8] = rAl1;
        *(bf16x8*)&Bh[srow][skb]     = rBh0;
        *(bf16x8*)&Bh[srow][skb + 8] = rBh1;
        *(bf16x8*)&Bl[srow][skb]     = rBl0;
        *(bf16x8*)&Bl[srow][skb + 8] = rBl1;
        __syncthreads();
        if (kt < 7) LOADT((kt + 1) * 32);   // prefetch next tile; lands during MFMA

        bf16x8 fah[4], fal[4];
#pragma unroll
        for (int mi = 0; mi < 4; mi++) {
            const int r = 64 * wm + 16 * mi + lrow;
            fah[mi] = *(const bf16x8*)&Ah[r][koff];
            fal[mi] = *(const bf16x8*)&Al[r][koff];
        }
#pragma unroll
        for (int ni = 0; ni < 4; ni++) {
            const int r = 64 * wn + 16 * ni + lrow;
            const bf16x8 fbh = *(const bf16x8*)&Bh[r][koff];
            const bf16x8 fbl = *(const bf16x8*)&Bl[r][koff];
#pragma unroll
            for (int mi = 0; mi < 4; mi++) {
                acc[mi][ni] = __builtin_amdgcn_mfma_f32_16x16x32_bf16(fah[mi], fbh, acc[mi][ni], 0, 0, 0);
                acc[mi][ni] = __builtin_amdgcn_mfma_f32_16x16x32_bf16(fal[mi], fbh, acc[mi][ni], 0, 0, 0);
                acc[mi][ni] = __builtin_amdgcn_mfma_f32_16x16x32_bf16(fah[mi], fbl, acc[mi][ni], 0, 0, 0);
            }
        }
    }
#undef LOADT

    // ---- epilogue
    const int rb = bm + 64 * wm + ((lane >> 4) << 2);
    const int cb = bn + 64 * wn + (lane & 15);
#pragma unroll
    for (int ni = 0; ni < 4; ni++) {
        const int col = cb + 16 * ni;
        const float ob = out_bias ? out_bias[col] : 0.f;
#pragma unroll
        for (int mi = 0; mi < 4; mi++) {
#pragma unroll
            for (int r = 0; r < 4; r++) {
                const int row = rb + 16 * mi + r;
                if (row < M) {
                    if (payload) {
                        payload[(size_t)row * 256 + col] = rn_bf16(acc[mi][ni][r]);
                    } else {
                        float vv = acc[mi][ni][r] + ob;
                        if (do_act) vv = (vv > 0.f) ? vv : slope * vv;
                        vv *= decay;
                        if (Cpack) {
                            const unsigned p = split2(vv);
                            Cpack[(size_t)row * 512 + col] = (unsigned short)(p >> 16);
                            Cpack[(size_t)row * 512 + 256 + col] = (unsigned short)(p & 0xffffu);
                        } else if (accum) {
                            C[(size_t)row * 256 + col] += vv;
                        } else {
                            C[(size_t)row * 256 + col] = vv;
                        }
                    }
                }
            }
        }
    }
}

// ---------------- alpha_s/alpha_d from bf16 payload: [N,8] head-wise dots
__global__ __launch_bounds__(256) void alpha_kernel(
    const unsigned short* __restrict__ payload, const float* __restrict__ att_s,
    const float* __restrict__ att_d, float* __restrict__ alpha_s, float* __restrict__ alpha_d)
{
    const int n = blockIdx.x;
    const int t = threadIdx.x;
    const float v  = bf2f(payload[(size_t)n * 256 + t]);
    float ps = v * att_s[t];
    float pd = v * att_d[t];
#pragma unroll
    for (int off = 16; off > 0; off >>= 1) {
        ps += __shfl_xor(ps, off, 32);
        pd += __shfl_xor(pd, off, 32);
    }
    if ((t & 31) == 0) {
        alpha_s[n * 8 + (t >> 5)] = ps;
        alpha_d[n * 8 + (t >> 5)] = pd;
    }
}

// ---------------- CSR build
__global__ __launch_bounds__(256) void hist_kernel(
    const int* __restrict__ edges, int* __restrict__ hist)
{
    const int gid = blockIdx.x * 256 + threadIdx.x;
    if (gid >= 3 * NEDGE) return;
    const int k = gid / NEDGE;
    const int e = gid - k * NEDGE;
    const int d = edges[(size_t)k * 2 * NEDGE + NEDGE + e];
    atomicAdd(&hist[k * NNODE + d], 1);
}

// hierarchical scan, level 1: block of 256 threads scans 1024 elems
__global__ __launch_bounds__(256) void scan_local(
    const int* __restrict__ hist, int* __restrict__ loc, int* __restrict__ bsums)
{
    const int hop = blockIdx.y;
    const int base = blockIdx.x * 1024;
    const int t = threadIdx.x;
    const int idx = base + t * 4;
    int4 v = make_int4(0, 0, 0, 0);
    if (idx < NNODE)   // NNODE%4==0 -> whole int4 in or out
        v = *reinterpret_cast<const int4*>(hist + (size_t)hop * NNODE + idx);
    const int s = v.x + v.y + v.z + v.w;
    __shared__ int buf[256];
    buf[t] = s;
    __syncthreads();
    for (int off = 1; off < 256; off <<= 1) {
        const int a = (t >= off) ? buf[t - off] : 0;
        __syncthreads();
        buf[t] += a;
        __syncthreads();
    }
    const int excl = buf[t] - s;
    if (t == 255) bsums[hop * 64 + blockIdx.x] = buf[255];
    if (idx < NNODE) {
        int* lp = loc + (size_t)hop * NNODE + idx;
        lp[0] = excl;
        lp[1] = excl + v.x;
        lp[2] = excl + v.x + v.y;
        lp[3] = excl + v.x + v.y + v.z;
    }
}

// level 2: scan the 49 block sums per hop (one wave per hop); writes rp[N]=total
__global__ __launch_bounds__(64) void scan_bsums(
    int* __restrict__ bsums, int* __restrict__ row_ptr)
{
    const int hop = blockIdx.x;
    const int lane = threadIdx.x;
    const int v = (lane < 49) ? bsums[hop * 64 + lane] : 0;
    int incl = v;
#pragma unroll
    for (int m = 1; m < 64; m <<= 1) {
        const int o = __shfl_up(incl, m, 64);
        if (lane >= m) incl += o;
    }
    if (lane < 49) bsums[hop * 64 + lane] = incl - v;   // exclusive
    if (lane == 48) row_ptr[hop * (NNODE + 1) + NNODE] = incl;
}

// level 3: add block offsets; writes row_ptr and cursor
__global__ __launch_bounds__(256) void scan_add(
    const int* __restrict__ loc, const int* __restrict__ bsums,
    int* __restrict__ row_ptr, int* __restrict__ cursor)
{
    const int gid = blockIdx.x * 256 + threadIdx.x;
    if (gid >= 3 * NNODE) return;
    const int k = gid / NNODE;
    const int i = gid - k * NNODE;
    const int v = loc[gid] + bsums[k * 64 + (i >> 10)];
    row_ptr[k * (NNODE + 1) + i] = v;
    cursor[gid] = v;
}

__global__ __launch_bounds__(256) void fill_kernel(
    const int* __restrict__ edges, int* __restrict__ cursor, int* __restrict__ col)
{
    const int gid = blockIdx.x * 256 + threadIdx.x;
    if (gid >= 3 * NEDGE) return;
    const int k = gid / NEDGE;
    const int e = gid - k * NEDGE;
    const int s = edges[(size_t)k * 2 * NEDGE + e];
    const int d = edges[(size_t)k * 2 * NEDGE + NEDGE + e];
    const int pos = atomicAdd(&cursor[k * NNODE + d], 1);
    col[(size_t)k * NEDGE + pos] = s;
}

// ---------------- fused GAT aggregate: one wave per dst, online softmax,
// gathers bf16 payload rows; adds gat_bias; writes split-pack bf16
__global__ __launch_bounds__(256) void gat_gather(
    const int* __restrict__ row_ptr, const int* __restrict__ col,
    const float* __restrict__ alpha_s, const float* __restrict__ alpha_d,
    const unsigned short* __restrict__ payload, const float* __restrict__ bias,
    unsigned short* __restrict__ outp)
{
    const int wave = (blockIdx.x * 256 + threadIdx.x) >> 6;
    const int lane = threadIdx.x & 63;
    if (wave >= NNODE) return;
    const int d = wave;
    const int h = lane >> 3;
    const float adh = alpha_d[d * 8 + h];
    const int beg = row_ptr[d];
    const int end = row_ptr[d + 1];

    float m = -3.402823466e38f;
    float s = 0.f;
    float a0 = 0.f, a1 = 0.f, a2 = 0.f, a3 = 0.f;

    for (int e = beg; e < end; ++e) {
        const int sidx = col[e];
        float v = alpha_s[sidx * 8 + h] + adh;
        v = (v > 0.f) ? v : 0.2f * v;
        if (v > m) {
            const float f = __expf(m - v);
            s *= f; a0 *= f; a1 *= f; a2 *= f; a3 *= f;
            m = v;
        }
        const float p = __expf(v - m);
        s += p;
        const u16x4 hv = *reinterpret_cast<const u16x4*>(payload + (size_t)sidx * 256 + lane * 4);
        a0 += p * bf2f(hv[0]); a1 += p * bf2f(hv[1]);
        a2 += p * bf2f(hv[2]); a3 += p * bf2f(hv[3]);
    }
    const float inv = 1.f / (s + 1e-16f);
    const float b0 = bias[lane * 4 + 0], b1 = bias[lane * 4 + 1];
    const float b2 = bias[lane * 4 + 2], b3 = bias[lane * 4 + 3];
    u16x4 hi, lo;
    unsigned p0 = split2(a0 * inv + b0);
    unsigned p1 = split2(a1 * inv + b1);
    unsigned p2 = split2(a2 * inv + b2);
    unsigned p3 = split2(a3 * inv + b3);
    hi[0] = (unsigned short)(p0 >> 16); lo[0] = (unsigned short)p0;
    hi[1] = (unsigned short)(p1 >> 16); lo[1] = (unsigned short)p1;
    hi[2] = (unsigned short)(p2 >> 16); lo[2] = (unsigned short)p2;
    hi[3] = (unsigned short)(p3 >> 16); lo[3] = (unsigned short)p3;
    *(u16x4*)(outp + (size_t)d * 512 + lane * 4) = hi;
    *(u16x4*)(outp + (size_t)d * 512 + 256 + lane * 4) = lo;
}

// ---------------- LayerNorm + residual; residual read from split-pack;
// writes split-pack (intermediate layer) or fp32 final output
__global__ __launch_bounds__(256) void ln_kernel(
    const float* __restrict__ accb, const unsigned short* __restrict__ hres,
    unsigned short* __restrict__ hout, float* __restrict__ final_out,
    const float* __restrict__ lns, const float* __restrict__ lnb)
{
    const int n = blockIdx.x;
    const int t = threadIdx.x;
    const float a = accb[(size_t)n * 256 + t];
    __shared__ float red[256];
    red[t] = a;
    __syncthreads();
    for (int off = 128; off > 0; off >>= 1) {
        if (t < off) red[t] += red[t + off];
        __syncthreads();
    }
    const float mu = red[0] * (1.f / 256.f);
    __syncthreads();
    const float dv = a - mu;
    red[t] = dv * dv;
    __syncthreads();
    for (int off = 128; off > 0; off >>= 1) {
        if (t < off) red[t] += red[t + off];
        __syncthreads();
    }
    const float var = red[0] * (1.f / 256.f);
    const float r = rsqrtf(var + 1e-5f);
    const float res = bf2f(hres[(size_t)n * 512 + t]) + bf2f(hres[(size_t)n * 512 + 256 + t]);
    const float o = dv * r * lns[t] + lnb[t] + res;
    if (final_out) {
        final_out[(size_t)n * 256 + t] = o;
    } else {
        const unsigned p = split2(o);
        hout[(size_t)n * 512 + t] = (unsigned short)(p >> 16);
        hout[(size_t)n * 512 + 256 + t] = (unsigned short)(p & 0xffffu);
    }
}

extern "C" void kernel_launch(void* const* d_in, const int* in_sizes, int n_in,
                              void* d_out, int out_size, void* d_ws, size_t ws_size,
                              hipStream_t stream) {
    const float* x      = (const float*)d_in[0];
    const int*   edges  = (const int*)  d_in[1];
    const float* lin1_w = (const float*)d_in[2];
    const float* lin1_b = (const float*)d_in[3];
    const float* gat_w  = (const float*)d_in[4];
    const float* att_s  = (const float*)d_in[5];
    const float* att_d  = (const float*)d_in[6];
    const float* gat_b  = (const float*)d_in[7];
    const float* dec_w  = (const float*)d_in[8];
    const float* dec_b  = (const float*)d_in[9];
    const float* ln_s   = (const float*)d_in[10];
    const float* ln_b   = (const float*)d_in[11];

    float* out = (float*)d_out;
    const size_t NF = (size_t)NNODE * 256;
    const size_t NP = (size_t)NNODE * 512;
    const size_t N8 = (size_t)NNODE * 8;

    float*          acc_buf = (float*)d_ws;
    unsigned short* payload = (unsigned short*)(acc_buf + NF);   // [N][256] bf16
    unsigned short* gpack   = payload + NF;                      // [N][512] hi|lo
    unsigned short* hpack   = gpack + NP;                        // [N][512] hi|lo
    unsigned short* wpack   = hpack + NP;                        // [13][256][512]
    float*          as_     = (float*)(wpack + (size_t)13 * 131072);
    float*          ad_     = as_ + N8;
    int*            hist    = (int*)(ad_ + N8);                  // [3][N]
    int*            cursor  = hist + 3 * NNODE;                  // [3][N]
    int*            row_ptr = cursor + 3 * NNODE;                // [3][N+1]
    int*            col     = row_ptr + 3 * (NNODE + 1);         // [3][E]
    int*            loc     = col + 3 * NEDGE;                   // [3][N]
    int*            bsums   = loc + 3 * NNODE;                   // [3][64]

    const float decays[3] = {DECAY0, DECAY1, DECAY2};

    dim3 gg((NNODE + 127) / 128, 2);
    dim3 tg(8, 8, 13);
    dim3 sg(49, 3);
    const int e3b = (3 * NEDGE + 255) / 256;
    const int n3b = (3 * NNODE + 255) / 256;
    const int gb  = (NNODE * 64 + 255) / 256;
    const int cvb = (NNODE * 32 + 255) / 256;

    transpose_split_w<<<tg, 256, 0, stream>>>(gat_w, dec_w, lin1_w, wpack);
    convert_split<<<cvb, 256, 0, stream>>>(x, gpack);

    // ---- CSR build (hierarchical scan)
    (void)hipMemsetAsync(hist, 0, 3 * NNODE * sizeof(int), stream);
    hist_kernel<<<e3b, 256, 0, stream>>>(edges, hist);
    scan_local<<<sg, 256, 0, stream>>>(hist, loc, bsums);
    scan_bsums<<<3, 64, 0, stream>>>(bsums, row_ptr);
    scan_add<<<n3b, 256, 0, stream>>>(loc, bsums, row_ptr, cursor);
    fill_kernel<<<e3b, 256, 0, stream>>>(edges, cursor, col);

    // hpack = split(leaky_relu(x @ lin1_w + lin1_b))
    gemm_pack<<<gg, 256, 0, stream>>>(gpack, wpack + (size_t)12 * 131072, nullptr, hpack, nullptr,
                                      NNODE, lin1_b, 0.01f, 1, 0, 1.f);

    for (int l = 0; l < 2; l++) {
        for (int k = 0; k < 3; k++) {
            const int lk = l * 3 + k;
            // payload = bf16(h @ gat_w[l,k])
            gemm_pack<<<gg, 256, 0, stream>>>(hpack, wpack + (size_t)lk * 131072,
                                              nullptr, nullptr, payload,
                                              NNODE, nullptr, 0.f, 0, 0, 1.f);
            alpha_kernel<<<NNODE, 256, 0, stream>>>(payload, att_s + lk * 256, att_d + lk * 256,
                                                    as_, ad_);
            // gpack = split(gat_aggregate + gat_bias)
            gat_gather<<<gb, 256, 0, stream>>>(row_ptr + (size_t)k * (NNODE + 1),
                                               col + (size_t)k * NEDGE,
                                               as_, ad_, payload, gat_b + lk * 256, gpack);
            // acc (+)= decay[k] * lrelu(gpack @ dec_w + dec_b)
            gemm_pack<<<gg, 256, 0, stream>>>(gpack, wpack + (size_t)(6 + lk) * 131072,
                                              acc_buf, nullptr, nullptr,
                                              NNODE, dec_b + lk * 256,
                                              0.01f, 1, (k > 0) ? 1 : 0, decays[k]);
        }
        ln_kernel<<<NNODE, 256, 0, stream>>>(acc_buf, hpack, hpack,
                                             (l == 1) ? out : nullptr,
                                             ln_s + l * 256, ln_b + l * 256);
    }
}